// Round 1
// baseline (149.382 us; speedup 1.0000x reference)
//
#include <hip/hip_runtime.h>
#include <math.h>

#define NG 1024
#define HH 256
#define WW 256
#define TILE_PX 64
#define HT 4
#define WT 4
#define NT 16
#define FOCAL_F 256.0f      // W / (2 * TAN_FOV) = 256 / 1.0
#define RADII_MULT_F 5.0f

// workspace layout (floats), sorted-by-depth SoA, each array NG long:
// 0: m2x  1: m2y  2: kexp(-0.5*log2e/s2sq)  3: op  4: r  5: g  6: b  7: dep
// 8: tilemask (uint bits reinterpreted)

__global__ __launch_bounds__(1024) void prep_sort_kernel(
    const float* __restrict__ means3d, const float* __restrict__ opacity,
    const float* __restrict__ scale3d, const float* __restrict__ features,
    const float* __restrict__ viewm, const float* __restrict__ projm,
    float* __restrict__ ws)
{
    __shared__ float s_m2x[NG], s_m2y[NG], s_k[NG], s_op[NG];
    __shared__ float s_r[NG], s_g[NG], s_b[NG];
    __shared__ float s_rminx[NG], s_rminy[NG], s_rmaxx[NG], s_rmaxy[NG];
    __shared__ float s_key[NG];
    __shared__ int   s_val[NG];

    const int i = threadIdx.x;

    // ---- preprocess gaussian i ----
    float V[16], P[16];
#pragma unroll
    for (int j = 0; j < 16; j++) { V[j] = viewm[j]; P[j] = projm[j]; }

    const float mx = means3d[i * 3 + 0];
    const float my = means3d[i * 3 + 1];
    const float mz = means3d[i * 3 + 2];

    // q = [mx,my,mz,1] @ V   (row-vector times row-major 4x4)
    const float q0 = mx * V[0] + my * V[4] + mz * V[8]  + V[12];
    const float q1 = mx * V[1] + my * V[5] + mz * V[9]  + V[13];
    const float q2 = mx * V[2] + my * V[6] + mz * V[10] + V[14];
    const float q3 = mx * V[3] + my * V[7] + mz * V[11] + V[15];
    // ph = q @ P
    const float h0 = q0 * P[0] + q1 * P[4] + q2 * P[8]  + q3 * P[12];
    const float h1 = q0 * P[1] + q1 * P[5] + q2 * P[9]  + q3 * P[13];
    const float h3 = q0 * P[3] + q1 * P[7] + q2 * P[11] + q3 * P[15];

    const float inv_w = 1.0f / (h3 + 1e-6f);
    const float ppx = h0 * inv_w;
    const float ppy = h1 * inv_w;
    const float m2x = ((ppx + 1.0f) * (float)WW - 1.0f) * 0.5f;
    const float m2y = ((ppy + 1.0f) * (float)HH - 1.0f) * 0.5f;

    const float depth = q2;      // p_view z
    const float tz = q2;         // t[...,2] equals p_view z (since homogeneous 1)

    const float s2 = scale3d[i] * FOCAL_F / tz;   // scale2d (both comps equal)
    const float radii = s2 * RADII_MULT_F;
    const float s2sq = s2 * s2;
    // exp(-0.5*d2/s2sq) == exp2(d2 * (-0.5*log2e/s2sq))
    const float kexp = -0.72134752044448170f / s2sq;

    const float rminx = fminf(fmaxf(m2x - radii, 0.0f), (float)(WW - 1));
    const float rminy = fminf(fmaxf(m2y - radii, 0.0f), (float)(HH - 1));
    const float rmaxx = fminf(fmaxf(m2x + radii, 0.0f), (float)(WW - 1));
    const float rmaxy = fminf(fmaxf(m2y + radii, 0.0f), (float)(HH - 1));

    s_m2x[i] = m2x; s_m2y[i] = m2y; s_k[i] = kexp; s_op[i] = opacity[i];
    s_r[i] = features[i * 3 + 0];
    s_g[i] = features[i * 3 + 1];
    s_b[i] = features[i * 3 + 2];
    s_rminx[i] = rminx; s_rminy[i] = rminy; s_rmaxx[i] = rmaxx; s_rmaxy[i] = rmaxy;
    s_key[i] = depth;
    s_val[i] = i;
    __syncthreads();

    // ---- bitonic sort (ascending by depth) ----
    for (int k = 2; k <= NG; k <<= 1) {
        for (int j = k >> 1; j > 0; j >>= 1) {
            const int ixj = i ^ j;
            if (ixj > i) {
                const float a = s_key[i];
                const float b = s_key[ixj];
                const bool up = ((i & k) == 0);
                const bool do_swap = up ? (a > b) : (a < b);
                if (do_swap) {
                    const int va = s_val[i], vb = s_val[ixj];
                    s_key[i] = b;  s_key[ixj] = a;
                    s_val[i] = vb; s_val[ixj] = va;
                }
            }
            __syncthreads();
        }
    }

    // ---- gather sorted SoA to workspace + per-gaussian tile mask ----
    const int g = s_val[i];
    ws[0 * NG + i] = s_m2x[g];
    ws[1 * NG + i] = s_m2y[g];
    ws[2 * NG + i] = s_k[g];
    ws[3 * NG + i] = s_op[g];
    ws[4 * NG + i] = s_r[g];
    ws[5 * NG + i] = s_g[g];
    ws[6 * NG + i] = s_b[g];
    ws[7 * NG + i] = s_key[i];   // sorted depth

    const float rmix = s_rminx[g], rmiy = s_rminy[g];
    const float rmax_ = s_rmaxx[g], rmay = s_rmaxy[g];
    unsigned m = 0u;
#pragma unroll
    for (int t = 0; t < NT; t++) {
        const float u0 = (float)((t % WT) * TILE_PX);
        const float v0 = (float)((t / WT) * TILE_PX);
        const float tlx = fmaxf(rmix, u0);
        const float tly = fmaxf(rmiy, v0);
        const float brx = fminf(rmax_, u0 + (float)TILE_PX - 1.0f);
        const float bry = fminf(rmay, v0 + (float)TILE_PX - 1.0f);
        if (brx > tlx && bry > tly) m |= (1u << t);
    }
    ((unsigned*)ws)[8 * NG + i] = m;
}

__global__ __launch_bounds__(256) void render_kernel(
    const float* __restrict__ ws, float* __restrict__ out)
{
    __shared__ float sm[9][256];

    const int tile  = blockIdx.x >> 4;   // 16 tiles
    const int strip = blockIdx.x & 15;   // 16 strips of 4 rows each
    const int u0 = (tile % WT) * TILE_PX;
    const int v0 = (tile / WT) * TILE_PX;
    const int lx = threadIdx.x & 63;
    const int ly = threadIdx.x >> 6;
    const int pxi = u0 + lx;
    const int pyi = v0 + strip * 4 + ly;
    const float px = (float)pxi;
    const float py = (float)pyi;
    const unsigned tilebit = 1u << tile;

    float T = 1.0f, cr = 0.0f, cg = 0.0f, cb = 0.0f, dsum = 0.0f, accsum = 0.0f;

    for (int base = 0; base < NG; base += 256) {
#pragma unroll
        for (int a = 0; a < 9; a++)
            sm[a][threadIdx.x] = ws[a * NG + base + threadIdx.x];
        __syncthreads();

        for (int j = 0; j < 256; j++) {
            const unsigned m = __float_as_uint(sm[8][j]);
            if (m & tilebit) {   // block-uniform branch: zero divergence
                const float dx = px - sm[0][j];
                const float dy = py - sm[1][j];
                const float d2 = dx * dx + dy * dy;
                const float gw = exp2f(d2 * sm[2][j]);
                const float alpha = fminf(gw * sm[3][j], 0.99f);
                const float w = alpha * T;
                cr += w * sm[4][j];
                cg += w * sm[5][j];
                cb += w * sm[6][j];
                dsum += w * sm[7][j];
                accsum += w;
                T -= alpha * T;   // T *= (1 - alpha)
            }
        }
        __syncthreads();
    }

    const float bg = 1.0f - accsum;
    cr = fminf(fmaxf(cr + bg, 0.0f), 1.0f);
    cg = fminf(fmaxf(cg + bg, 0.0f), 1.0f);
    cb = fminf(fmaxf(cb + bg, 0.0f), 1.0f);

    const int pix = pyi * WW + pxi;
    out[pix * 3 + 0] = cr;
    out[pix * 3 + 1] = cg;
    out[pix * 3 + 2] = cb;
    out[WW * HH * 3 + pix] = dsum;
    out[WW * HH * 4 + pix] = accsum;
}

extern "C" void kernel_launch(void* const* d_in, const int* in_sizes, int n_in,
                              void* d_out, int out_size, void* d_ws, size_t ws_size,
                              hipStream_t stream) {
    const float* means3d  = (const float*)d_in[0];
    const float* opacity  = (const float*)d_in[1];
    const float* scale3d  = (const float*)d_in[2];
    const float* features = (const float*)d_in[3];
    const float* viewm    = (const float*)d_in[4];
    const float* projm    = (const float*)d_in[5];
    float* ws  = (float*)d_ws;
    float* out = (float*)d_out;

    prep_sort_kernel<<<1, 1024, 0, stream>>>(means3d, opacity, scale3d, features,
                                             viewm, projm, ws);
    render_kernel<<<256, 256, 0, stream>>>(ws, out);
}

// Round 2
// 101.978 us; speedup vs baseline: 1.4648x; 1.4648x over previous
//
#include <hip/hip_runtime.h>
#include <math.h>

#define NG 1024
#define HH 256
#define WW 256
#define TILE_PX 64
#define WT 4
#define FOCAL_F 256.0f      // W / (2 * TAN_FOV)
#define RADII_MULT_F 5.0f

// ws layout: 12 SoA arrays of NG floats, sorted by depth rank:
// 0: rminx 1: rmaxx 2: rminy 3: rmaxy
// 4: m2x   5: m2y   6: kexp  7: op   8: r  9: g  10: b  11: dep

__global__ __launch_bounds__(64) void prep_rank_kernel(
    const float* __restrict__ means3d, const float* __restrict__ opacity,
    const float* __restrict__ scale3d, const float* __restrict__ features,
    const float* __restrict__ viewm, const float* __restrict__ projm,
    float* __restrict__ ws)
{
    __shared__ float s_dep[NG];

    const int l = threadIdx.x;
    const int gid = blockIdx.x * 64 + l;

    // view-matrix column 2 (for depth q2)
    const float v2 = viewm[2], v6 = viewm[6], v10 = viewm[10], v14 = viewm[14];

    // each lane computes depths for 16 gaussians
#pragma unroll
    for (int c = 0; c < NG / 64; c++) {
        const int g = c * 64 + l;
        const float mx = means3d[g * 3 + 0];
        const float my = means3d[g * 3 + 1];
        const float mz = means3d[g * 3 + 2];
        s_dep[g] = mx * v2 + my * v6 + mz * v10 + v14;
    }
    __syncthreads();

    // rank of my gaussian (stable argsort semantics)
    const float myd = s_dep[gid];
    int rank = 0;
#pragma unroll 4
    for (int j = 0; j < NG; j++) {
        const float d = s_dep[j];
        rank += (d < myd || (d == myd && j < gid)) ? 1 : 0;
    }

    // full attributes for my gaussian
    float V[16], P[16];
#pragma unroll
    for (int j = 0; j < 16; j++) { V[j] = viewm[j]; P[j] = projm[j]; }

    const float mx = means3d[gid * 3 + 0];
    const float my = means3d[gid * 3 + 1];
    const float mz = means3d[gid * 3 + 2];

    const float q0 = mx * V[0] + my * V[4] + mz * V[8]  + V[12];
    const float q1 = mx * V[1] + my * V[5] + mz * V[9]  + V[13];
    const float q2 = mx * V[2] + my * V[6] + mz * V[10] + V[14];
    const float q3 = mx * V[3] + my * V[7] + mz * V[11] + V[15];
    const float h0 = q0 * P[0] + q1 * P[4] + q2 * P[8]  + q3 * P[12];
    const float h1 = q0 * P[1] + q1 * P[5] + q2 * P[9]  + q3 * P[13];
    const float h3 = q0 * P[3] + q1 * P[7] + q2 * P[11] + q3 * P[15];

    const float inv_w = 1.0f / (h3 + 1e-6f);
    const float m2x = ((h0 * inv_w + 1.0f) * (float)WW - 1.0f) * 0.5f;
    const float m2y = ((h1 * inv_w + 1.0f) * (float)HH - 1.0f) * 0.5f;

    const float s2 = scale3d[gid] * FOCAL_F / q2;
    const float radii = s2 * RADII_MULT_F;
    const float kexp = -0.72134752044448170f / (s2 * s2);  // -0.5*log2(e)/s2sq

    const float rminx = fminf(fmaxf(m2x - radii, 0.0f), (float)(WW - 1));
    const float rminy = fminf(fmaxf(m2y - radii, 0.0f), (float)(HH - 1));
    const float rmaxx = fminf(fmaxf(m2x + radii, 0.0f), (float)(WW - 1));
    const float rmaxy = fminf(fmaxf(m2y + radii, 0.0f), (float)(HH - 1));

    ws[0 * NG + rank] = rminx;
    ws[1 * NG + rank] = rmaxx;
    ws[2 * NG + rank] = rminy;
    ws[3 * NG + rank] = rmaxy;
    ws[4 * NG + rank] = m2x;
    ws[5 * NG + rank] = m2y;
    ws[6 * NG + rank] = kexp;
    ws[7 * NG + rank] = opacity[gid];
    ws[8 * NG + rank] = features[gid * 3 + 0];
    ws[9 * NG + rank] = features[gid * 3 + 1];
    ws[10 * NG + rank] = features[gid * 3 + 2];
    ws[11 * NG + rank] = q2;
}

// one wave per pixel row-of-tile: 1024 blocks = 16 tiles x 64 rows
__global__ __launch_bounds__(64) void render_kernel(
    const float* __restrict__ ws, float* __restrict__ out)
{
    __shared__ float s_list[NG][8];   // compacted: m2x m2y k op r g b dep

    const int tile = blockIdx.x >> 6;        // 16 tiles
    const int row  = blockIdx.x & 63;        // row within tile
    const int u0 = (tile % WT) * TILE_PX;
    const int v0 = (tile / WT) * TILE_PX;
    const int l = threadIdx.x;
    const int pxi = u0 + l;
    const int pyi = v0 + row;
    const float px = (float)pxi;
    const float py = (float)pyi;
    const float u0f = (float)u0;
    const float u1f = (float)(u0 + TILE_PX - 1);

    // ---- ballot-compact gaussians relevant to this row (order-preserving) ----
    int cnt = 0;
    for (int base = 0; base < NG; base += 64) {
        const int g = base + l;
        const float rminx = ws[0 * NG + g];
        const float rmaxx = ws[1 * NG + g];
        const float rminy = ws[2 * NG + g];
        const float rmaxy = ws[3 * NG + g];
        const bool pass = (fminf(rmaxx, u1f) > fmaxf(rminx, u0f)) &&
                          (rminy <= py) && (py <= rmaxy);
        const unsigned long long m = __ballot(pass);
        if (pass) {
            const int off = cnt + __popcll(m & ((1ull << l) - 1ull));
            s_list[off][0] = ws[4 * NG + g];
            s_list[off][1] = ws[5 * NG + g];
            s_list[off][2] = ws[6 * NG + g];
            s_list[off][3] = ws[7 * NG + g];
            s_list[off][4] = ws[8 * NG + g];
            s_list[off][5] = ws[9 * NG + g];
            s_list[off][6] = ws[10 * NG + g];
            s_list[off][7] = ws[11 * NG + g];
        }
        cnt += __popcll(m);
    }
    __syncthreads();   // single wave: orders LDS writes before reads

    // ---- front-to-back blend over compacted list (broadcast LDS reads) ----
    float T = 1.0f, cr = 0.0f, cg = 0.0f, cb = 0.0f, dsum = 0.0f, accsum = 0.0f;
    for (int e = 0; e < cnt; e++) {
        const float dx = px - s_list[e][0];
        const float dy = py - s_list[e][1];
        const float d2 = dx * dx + dy * dy;
        const float gw = exp2f(d2 * s_list[e][2]);
        const float alpha = fminf(gw * s_list[e][3], 0.99f);
        const float w = alpha * T;
        cr += w * s_list[e][4];
        cg += w * s_list[e][5];
        cb += w * s_list[e][6];
        dsum += w * s_list[e][7];
        accsum += w;
        T -= alpha * T;
    }

    const float bg = 1.0f - accsum;
    cr = fminf(fmaxf(cr + bg, 0.0f), 1.0f);
    cg = fminf(fmaxf(cg + bg, 0.0f), 1.0f);
    cb = fminf(fmaxf(cb + bg, 0.0f), 1.0f);

    const int pix = pyi * WW + pxi;
    out[pix * 3 + 0] = cr;
    out[pix * 3 + 1] = cg;
    out[pix * 3 + 2] = cb;
    out[WW * HH * 3 + pix] = dsum;
    out[WW * HH * 4 + pix] = accsum;
}

extern "C" void kernel_launch(void* const* d_in, const int* in_sizes, int n_in,
                              void* d_out, int out_size, void* d_ws, size_t ws_size,
                              hipStream_t stream) {
    const float* means3d  = (const float*)d_in[0];
    const float* opacity  = (const float*)d_in[1];
    const float* scale3d  = (const float*)d_in[2];
    const float* features = (const float*)d_in[3];
    const float* viewm    = (const float*)d_in[4];
    const float* projm    = (const float*)d_in[5];
    float* ws  = (float*)d_ws;
    float* out = (float*)d_out;

    prep_rank_kernel<<<16, 64, 0, stream>>>(means3d, opacity, scale3d, features,
                                            viewm, projm, ws);
    render_kernel<<<1024, 64, 0, stream>>>(ws, out);
}